// Round 3
// baseline (813.167 us; speedup 1.0000x reference)
//
#include <hip/hip_runtime.h>
#include <hip/hip_cooperative_groups.h>
#include <math.h>

namespace cg = cooperative_groups;

#define HW 16384
#define NPTS 1024
#define LOG_N 6.2383246250395075
#define RHO_C 0.09
#define SCALE_F 16384.0f
#define INV_SCALE2 3.725290298461914e-09  // 2^-28, exact
#define NTILES 36                          // 8x8 upper triangle

typedef _Float16 f16x8 __attribute__((ext_vector_type(8)));
typedef float f32x4 __attribute__((ext_vector_type(4)));

typedef __attribute__((address_space(1))) const void gvoid_t;
typedef __attribute__((address_space(3))) void svoid_t;

__device__ __forceinline__ void tri_map(int tt, int& ti, int& tj) {
  int a = 0, r = tt;
  while (r >= 8 - a) { r -= 8 - a; ++a; }
  ti = a; tj = a + r;
}

// ---------------------------------------------------------------------------
// Convert fp32 P=[nd;gt] (1024 x 16384) into scaled fp16 hi/lo split, stored
// K-tiled: hi_t[k64][row][64], 8-elem groups pre-swizzled by g ^ (row&7) so
// the GEMM's linear global_load_lds yields a conflict-free LDS image.
// ---------------------------------------------------------------------------
__global__ __launch_bounds__(256)
void convert_split_k(const float* __restrict__ nd, const float* __restrict__ gt,
                     _Float16* __restrict__ hi_t, _Float16* __restrict__ lo_t) {
  const int tid = blockIdx.x * 256 + threadIdx.x;  // 0 .. 262143
  const int r = tid & 1023;
  const int k64 = tid >> 10;
  const float* __restrict__ src =
      (r < 512 ? nd + (size_t)r * HW : gt + (size_t)(r - 512) * HW) + k64 * 64;
  const size_t obase = ((size_t)k64 * 1024 + r) * 64;
  const int sw = r & 7;
#pragma unroll
  for (int g = 0; g < 8; ++g) {
    const float4 v0 = *(const float4*)(src + g * 8);
    const float4 v1 = *(const float4*)(src + g * 8 + 4);
    const float x[8] = {v0.x, v0.y, v0.z, v0.w, v1.x, v1.y, v1.z, v1.w};
    f16x8 h, l;
#pragma unroll
    for (int j = 0; j < 8; ++j) {
      const float xs = x[j] * SCALE_F;
      const _Float16 hh = (_Float16)xs;
      h[j] = hh;
      l[j] = (_Float16)(xs - (float)hh);
    }
    *(f16x8*)(hi_t + obase + (size_t)(g ^ sw) * 8) = h;
    *(f16x8*)(lo_t + obase + (size_t)(g ^ sw) * 8) = l;
  }
}

// ---------------------------------------------------------------------------
// Upper-triangle tiles only (G symmetric). 128x128 tile, BK=64, 4 waves,
// 3-pass f16 split MFMA, split-K over gridDim.y. part[c][tt][128*128].
// ---------------------------------------------------------------------------
__global__ __launch_bounds__(256)
void gemm_mfma_k(const _Float16* __restrict__ hi_t, const _Float16* __restrict__ lo_t,
                 float* __restrict__ part) {
  __shared__ __align__(16) _Float16 Ahi[128 * 64];
  __shared__ __align__(16) _Float16 Alo[128 * 64];
  __shared__ __align__(16) _Float16 Bhi[128 * 64];
  __shared__ __align__(16) _Float16 Blo[128 * 64];

  const int tt = blockIdx.x, c = blockIdx.y;
  int ti, tj;
  tri_map(tt, ti, tj);
  const int nkt = 256 / gridDim.y;  // k64-tiles per chunk
  const int t = threadIdx.x;
  const int lane = t & 63, w = t >> 6;
  const int wr = w >> 1, wc = w & 1;

  f32x4 acc[4][4];
#pragma unroll
  for (int m = 0; m < 4; ++m)
#pragma unroll
    for (int n = 0; n < 4; ++n) acc[m][n] = (f32x4){0.f, 0.f, 0.f, 0.f};

  const int rlow = lane & 15, g0 = lane >> 4;
  const int kt0 = c * nkt;

  for (int ks = 0; ks < nkt; ++ks) {
    const size_t ktbase = (size_t)(kt0 + ks) * (1024 * 64);
    const _Float16* __restrict__ sAh = hi_t + ktbase + (size_t)ti * 128 * 64;
    const _Float16* __restrict__ sAl = lo_t + ktbase + (size_t)ti * 128 * 64;
    const _Float16* __restrict__ sBh = hi_t + ktbase + (size_t)tj * 128 * 64;
    const _Float16* __restrict__ sBl = lo_t + ktbase + (size_t)tj * 128 * 64;
#pragma unroll
    for (int q = 0; q < 4; ++q) {
      const int off = (w * 4 + q) * 1024 + lane * 16;  // bytes
      __builtin_amdgcn_global_load_lds((gvoid_t*)((const char*)sAh + off),
                                       (svoid_t*)((char*)Ahi + (w * 4 + q) * 1024), 16, 0, 0);
      __builtin_amdgcn_global_load_lds((gvoid_t*)((const char*)sAl + off),
                                       (svoid_t*)((char*)Alo + (w * 4 + q) * 1024), 16, 0, 0);
      __builtin_amdgcn_global_load_lds((gvoid_t*)((const char*)sBh + off),
                                       (svoid_t*)((char*)Bhi + (w * 4 + q) * 1024), 16, 0, 0);
      __builtin_amdgcn_global_load_lds((gvoid_t*)((const char*)sBl + off),
                                       (svoid_t*)((char*)Blo + (w * 4 + q) * 1024), 16, 0, 0);
    }
    __syncthreads();

#pragma unroll
    for (int kk = 0; kk < 2; ++kk) {
      const int g = kk * 4 + g0;
      f16x8 fah[4], fal[4], fbh[4], fbl[4];
#pragma unroll
      for (int m = 0; m < 4; ++m) {
        const int ra = wr * 64 + m * 16 + rlow;
        const int pa = (g ^ (ra & 7)) * 8;
        fah[m] = *(const f16x8*)(Ahi + ra * 64 + pa);
        fal[m] = *(const f16x8*)(Alo + ra * 64 + pa);
        const int rb = wc * 64 + m * 16 + rlow;
        const int pb = (g ^ (rb & 7)) * 8;
        fbh[m] = *(const f16x8*)(Bhi + rb * 64 + pb);
        fbl[m] = *(const f16x8*)(Blo + rb * 64 + pb);
      }
#pragma unroll
      for (int m = 0; m < 4; ++m)
#pragma unroll
        for (int n = 0; n < 4; ++n) {
          acc[m][n] = __builtin_amdgcn_mfma_f32_16x16x32_f16(fah[m], fbh[n], acc[m][n], 0, 0, 0);
          acc[m][n] = __builtin_amdgcn_mfma_f32_16x16x32_f16(fal[m], fbh[n], acc[m][n], 0, 0, 0);
          acc[m][n] = __builtin_amdgcn_mfma_f32_16x16x32_f16(fah[m], fbl[n], acc[m][n], 0, 0, 0);
        }
    }
    __syncthreads();
  }

  // C/D layout: col = lane&15, row = (lane>>4)*4 + q (m89-verified)
  float* __restrict__ dst = part + ((size_t)c * NTILES + tt) * 16384;
  const int c_locb = wc * 64 + rlow;
  const int r_locb = wr * 64 + g0 * 4;
#pragma unroll
  for (int m = 0; m < 4; ++m)
#pragma unroll
    for (int q = 0; q < 4; ++q) {
      const int rl = r_locb + m * 16 + q;
#pragma unroll
      for (int n = 0; n < 4; ++n)
        dst[rl * 128 + c_locb + n * 16] = acc[m][n][q];
    }
}

// ---------------------------------------------------------------------------
// Sum split-K partials (fp64), unscale, write G tile + mirrored tile (LDS
// transpose, pad 129 = conflict-free), extract diagonal.
// Grid: 36 tiles x 4 slabs of 32 rows.
// ---------------------------------------------------------------------------
__global__ __launch_bounds__(256)
void reduce_tiles_k(const float* __restrict__ part, float* __restrict__ G,
                    float* __restrict__ diag, int nsplit) {
  __shared__ float sl[32][129];
  const int blk = blockIdx.x;  // 0..143
  const int tt = blk >> 2, s = blk & 3;
  int ti, tj;
  tri_map(tt, ti, tj);
  const int t = threadIdx.x;
  const int base_in = tt * 16384 + s * 4096;

  float vals[16];
#pragma unroll
  for (int j = 0; j < 16; ++j) {
    const int idx = j * 256 + t;  // 0..4095 within slab
    double a = 0.0;
    for (int c = 0; c < nsplit; ++c)
      a += (double)part[(size_t)c * (NTILES * 16384) + base_in + idx];
    vals[j] = (float)(a * INV_SCALE2);
  }
#pragma unroll
  for (int j = 0; j < 16; ++j) {
    const int idx = j * 256 + t;
    const int r = idx >> 7, cl = idx & 127;
    const int R = ti * 128 + s * 32 + r, C = tj * 128 + cl;
    G[(size_t)R * NPTS + C] = vals[j];
    if (R == C) diag[R] = vals[j];
    sl[r][cl] = vals[j];
  }
  if (ti == tj) return;
  __syncthreads();
#pragma unroll
  for (int j = 0; j < 16; ++j) {
    const int idx = j * 256 + t;
    const int r = idx & 31, cl = idx >> 5;
    G[(size_t)(tj * 128 + cl) * NPTS + ti * 128 + s * 32 + r] = sl[r][cl];
  }
}

// ---------------------------------------------------------------------------
// Fused Sinkhorn: all 11 phases + loss in one cooperative kernel.
// 512 blocks x 256 threads; 1 wave = 1 row-task (2048 tasks). C-row cached
// in registers across phases; grid.sync() between phases.
// pots: buf0 = pots[0..2048), buf1 = pots[2048..4096).
// ---------------------------------------------------------------------------
__global__ __launch_bounds__(256)
void sinkhorn_all_k(const float* __restrict__ G, const float* __restrict__ diag,
                    double* __restrict__ pots, float* __restrict__ out, int out_size) {
  const int w = threadIdx.x >> 6, lane = threadIdx.x & 63;
  const int id = blockIdx.x * 4 + w;  // 0..2047
  const int which = id >> 9, r = id & 511;
  int row_pt, col_base, pot_idx;
  if (which == 0)      { row_pt = r;       col_base = 512; pot_idx = 1; }
  else if (which == 1) { row_pt = 512 + r; col_base = 0;   pot_idx = 0; }
  else if (which == 2) { row_pt = r;       col_base = 0;   pot_idx = 2; }
  else                 { row_pt = 512 + r; col_base = 512; pot_idx = 3; }

  const double dr = (double)diag[row_pt];
  const float* __restrict__ Grow = G + (size_t)row_pt * NPTS + col_base;
  const float* __restrict__ dcol = diag + col_base;
  double Creg[8];
#pragma unroll
  for (int u = 0; u < 8; ++u) {
    const int j = lane + u * 64;
    Creg[u] = 0.5 * (dr + (double)dcol[j]) - (double)Grow[j];
  }

  cg::grid_group grid = cg::this_grid();
  double* buf0 = pots;
  double* buf1 = pots + 2048;

  const double eps_tab[11] = {1.0, 1.0, 1.0, 0.25, 0.0625, 0.015625,
                              0.00390625, 0.0009765625, 0.000244140625, 1e-4, 1e-4};
#pragma unroll
  for (int p = 0; p < 11; ++p) {
    const double eps = eps_tab[p];
    const double inv_eps = 1.0 / eps;
    const double damp = 1.0 / (1.0 + eps / RHO_C);
    const int use_pot = (p > 0);
    const int do_avg = (p >= 1 && p <= 9);
    const double* __restrict__ sp = (p & 1) ? buf0 : buf1;
    double* __restrict__ dp = (p & 1) ? buf1 : buf0;
    const double* __restrict__ pot = sp + pot_idx * 512;

    double arg[8];
    double m = -1.0e300;
#pragma unroll
    for (int u = 0; u < 8; ++u) {
      const double pv = use_pot ? pot[lane + u * 64] : 0.0;
      const double a = (pv - Creg[u]) * inv_eps - LOG_N;
      arg[u] = a;
      m = fmax(m, a);
    }
#pragma unroll
    for (int off = 32; off > 0; off >>= 1) m = fmax(m, __shfl_xor(m, off));
    double s = 0.0;
#pragma unroll
    for (int u = 0; u < 8; ++u) s += exp(arg[u] - m);
#pragma unroll
    for (int off = 32; off > 0; off >>= 1) s += __shfl_xor(s, off);
    if (lane == 0) {
      const double val = -eps * (m + log(s)) * damp;
      dp[which * 512 + r] = do_avg ? 0.5 * (sp[which * 512 + r] + val) : val;
    }
    grid.sync();
  }

  // loss from buf0 (phase 10 wrote buf0), block 0 only
  if (blockIdx.x == 0) {
    const int t = threadIdx.x;
    double s = 0.0;
    for (int i = t; i < 512; i += 256) {
      const double f_ba = buf0[i];
      const double g_ab = buf0[512 + i];
      const double f_aa = buf0[1024 + i];
      const double g_bb = buf0[1536 + i];
      s += (exp(-f_aa / RHO_C) - exp(-f_ba / RHO_C)) +
           (exp(-g_bb / RHO_C) - exp(-g_ab / RHO_C));
    }
#pragma unroll
    for (int off = 32; off > 0; off >>= 1) s += __shfl_xor(s, off);
    __shared__ double wsum[4];
    if ((t & 63) == 0) wsum[t >> 6] = s;
    __syncthreads();
    if (t == 0) {
      const double tot = wsum[0] + wsum[1] + wsum[2] + wsum[3];
      out[0] = (float)((RHO_C + 1e-4 * 0.5) * tot * (1.0 / 512.0));
      for (int i = 1; i < out_size; ++i) out[i] = 0.f;
    }
  }
}

// ---------------- fallback (non-cooperative) Sinkhorn path ------------------
__global__ __launch_bounds__(64)
void sinkhorn_phase_k(const float* __restrict__ G, const float* __restrict__ diag,
                      const double* __restrict__ src, double* __restrict__ dst,
                      double eps, double inv_eps, double damp, int use_pot,
                      int do_avg) {
  const int id = blockIdx.x;
  const int which = id >> 9;
  const int r = id & 511;
  int row_pt, col_base, pot_idx;
  if (which == 0)      { row_pt = r;       col_base = 512; pot_idx = 1; }
  else if (which == 1) { row_pt = 512 + r; col_base = 0;   pot_idx = 0; }
  else if (which == 2) { row_pt = r;       col_base = 0;   pot_idx = 2; }
  else                 { row_pt = 512 + r; col_base = 512; pot_idx = 3; }

  const int lane = threadIdx.x;
  const double dr = (double)diag[row_pt];
  const double* __restrict__ pot = src + pot_idx * 512;
  const float* __restrict__ Grow = G + (size_t)row_pt * NPTS + col_base;
  const float* __restrict__ dcol = diag + col_base;

  double arg[8];
  double m = -1.0e300;
#pragma unroll
  for (int u = 0; u < 8; ++u) {
    const int j = lane + u * 64;
    const double C = 0.5 * (dr + (double)dcol[j]) - (double)Grow[j];
    const double p = use_pot ? pot[j] : 0.0;
    const double a = (p - C) * inv_eps - LOG_N;
    arg[u] = a;
    m = fmax(m, a);
  }
#pragma unroll
  for (int off = 32; off > 0; off >>= 1) m = fmax(m, __shfl_xor(m, off));
  double s = 0.0;
#pragma unroll
  for (int u = 0; u < 8; ++u) s += exp(arg[u] - m);
#pragma unroll
  for (int off = 32; off > 0; off >>= 1) s += __shfl_xor(s, off);
  if (lane == 0) {
    const double lse = m + log(s);
    const double val = -eps * lse * damp;
    dst[which * 512 + r] = do_avg ? 0.5 * (src[which * 512 + r] + val) : val;
  }
}

__global__ __launch_bounds__(256)
void loss_k(const double* __restrict__ pot, float* __restrict__ out, int out_size,
            double w) {
  const int t = threadIdx.x;
  double s = 0.0;
  for (int i = t; i < 512; i += 256) {
    s += (exp(-pot[1024 + i] / RHO_C) - exp(-pot[i] / RHO_C)) +
         (exp(-pot[1536 + i] / RHO_C) - exp(-pot[512 + i] / RHO_C));
  }
#pragma unroll
  for (int off = 32; off > 0; off >>= 1) s += __shfl_xor(s, off);
  __shared__ double wsum[4];
  if ((t & 63) == 0) wsum[t >> 6] = s;
  __syncthreads();
  if (t == 0) {
    out[0] = (float)(w * (wsum[0] + wsum[1] + wsum[2] + wsum[3]) * (1.0 / 512.0));
    for (int i = 1; i < out_size; ++i) out[i] = 0.f;
  }
}

extern "C" void kernel_launch(void* const* d_in, const int* in_sizes, int n_in,
                              void* d_out, int out_size, void* d_ws, size_t ws_size,
                              hipStream_t stream) {
  const float* nd = (const float*)d_in[1];
  const float* gt = (const float*)d_in[2];
  float* out = (float*)d_out;
  char* ws = (char*)d_ws;

  const size_t GM = (size_t)NPTS * NPTS;     // 1M elems
  const size_t P16 = (size_t)NPTS * HW * 2;  // 32 MB per half
  int nsplit = 32;
  while (nsplit > 1 &&
         2 * P16 + (size_t)nsplit * NTILES * 16384 * 4 + GM * 4 + 65536 > ws_size)
    nsplit >>= 1;

  _Float16* hi_t = (_Float16*)ws;
  _Float16* lo_t = (_Float16*)(ws + P16);
  float* part = (float*)(ws + 2 * P16);
  const size_t partsz = (size_t)nsplit * NTILES * 16384 * 4;
  float* G = (float*)(ws + 2 * P16 + partsz);
  float* diag = (float*)(ws + 2 * P16 + partsz + GM * 4);
  double* pots = (double*)(ws + 2 * P16 + partsz + GM * 4 + 8192);

  convert_split_k<<<1024, 256, 0, stream>>>(nd, gt, hi_t, lo_t);
  gemm_mfma_k<<<dim3(NTILES, nsplit), 256, 0, stream>>>(hi_t, lo_t, part);
  reduce_tiles_k<<<144, 256, 0, stream>>>(part, G, diag, nsplit);

  int coop = 0;
  hipDeviceGetAttribute(&coop, hipDeviceAttributeCooperativeLaunch, 0);
  if (coop) {
    void* args[] = {(void*)&G, (void*)&diag, (void*)&pots, (void*)&out, (void*)&out_size};
    hipLaunchCooperativeKernel((void*)sinkhorn_all_k, dim3(512), dim3(256), args, 0, stream);
  } else {
    const double eps_list[9] = {1.0, 1.0, 0.25, 0.0625, 0.015625,
                                0.00390625, 0.0009765625, 0.000244140625, 1e-4};
    double* p0 = pots;
    double* p1 = pots + 2048;
    {
      const double eps = 1.0, d = 1.0 / (1.0 + eps / RHO_C);
      sinkhorn_phase_k<<<2048, 64, 0, stream>>>(G, diag, p1, p0, eps, 1.0 / eps, d, 0, 0);
    }
    double* src = p0;
    double* dst = p1;
    for (int k = 0; k < 9; ++k) {
      const double eps = eps_list[k], d = 1.0 / (1.0 + eps / RHO_C);
      sinkhorn_phase_k<<<2048, 64, 0, stream>>>(G, diag, src, dst, eps, 1.0 / eps, d, 1, 1);
      double* tmp = src; src = dst; dst = tmp;
    }
    {
      const double eps = 1e-4, d = 1.0 / (1.0 + eps / RHO_C);
      sinkhorn_phase_k<<<2048, 64, 0, stream>>>(G, diag, src, dst, eps, 1.0 / eps, d, 1, 0);
      double* tmp = src; src = dst; dst = tmp;
    }
    loss_k<<<1, 256, 0, stream>>>(src, out, out_size, RHO_C + 1e-4 * 0.5);
  }
}

// Round 4
// 252.019 us; speedup vs baseline: 3.2266x; 3.2266x over previous
//
#include <hip/hip_runtime.h>
#include <math.h>

#define HW 16384
#define NPTS 1024
#define LOG_N 6.2383246250395075
#define RHO_C 0.09
#define SCALE_F 16384.0f
#define INV_SCALE2 3.725290298461914e-09  // 2^-28, exact
#define NTILES 36                          // 8x8 upper triangle

typedef _Float16 f16x8 __attribute__((ext_vector_type(8)));
typedef float f32x4 __attribute__((ext_vector_type(4)));

typedef __attribute__((address_space(1))) const void gvoid_t;
typedef __attribute__((address_space(3))) void svoid_t;

__device__ __forceinline__ void tri_map(int tt, int& ti, int& tj) {
  int a = 0, r = tt;
  while (r >= 8 - a) { r -= 8 - a; ++a; }
  ti = a; tj = a + r;
}

// ---------------------------------------------------------------------------
// Convert fp32 P=[nd;gt] (1024 x 16384) into scaled fp16 hi/lo split, stored
// K-tiled: hi_t[k64][row][64], 8-elem groups pre-swizzled by g ^ (row&7) so
// the GEMM's linear global_load_lds yields a conflict-free LDS image.
// ---------------------------------------------------------------------------
__global__ __launch_bounds__(256)
void convert_split_k(const float* __restrict__ nd, const float* __restrict__ gt,
                     _Float16* __restrict__ hi_t, _Float16* __restrict__ lo_t) {
  const int tid = blockIdx.x * 256 + threadIdx.x;  // 0 .. 262143
  const int r = tid & 1023;
  const int k64 = tid >> 10;
  const float* __restrict__ src =
      (r < 512 ? nd + (size_t)r * HW : gt + (size_t)(r - 512) * HW) + k64 * 64;
  const size_t obase = ((size_t)k64 * 1024 + r) * 64;
  const int sw = r & 7;
#pragma unroll
  for (int g = 0; g < 8; ++g) {
    const float4 v0 = *(const float4*)(src + g * 8);
    const float4 v1 = *(const float4*)(src + g * 8 + 4);
    const float x[8] = {v0.x, v0.y, v0.z, v0.w, v1.x, v1.y, v1.z, v1.w};
    f16x8 h, l;
#pragma unroll
    for (int j = 0; j < 8; ++j) {
      const float xs = x[j] * SCALE_F;
      const _Float16 hh = (_Float16)xs;
      h[j] = hh;
      l[j] = (_Float16)(xs - (float)hh);
    }
    *(f16x8*)(hi_t + obase + (size_t)(g ^ sw) * 8) = h;
    *(f16x8*)(lo_t + obase + (size_t)(g ^ sw) * 8) = l;
  }
}

// ---------------------------------------------------------------------------
// Upper-triangle tiles only (G symmetric). 128x128 tile, BK=64, 4 waves,
// 3-pass f16 split MFMA, split-K over gridDim.y. part[c][tt][128*128].
// ---------------------------------------------------------------------------
__global__ __launch_bounds__(256)
void gemm_mfma_k(const _Float16* __restrict__ hi_t, const _Float16* __restrict__ lo_t,
                 float* __restrict__ part) {
  __shared__ __align__(16) _Float16 Ahi[128 * 64];
  __shared__ __align__(16) _Float16 Alo[128 * 64];
  __shared__ __align__(16) _Float16 Bhi[128 * 64];
  __shared__ __align__(16) _Float16 Blo[128 * 64];

  const int tt = blockIdx.x, c = blockIdx.y;
  int ti, tj;
  tri_map(tt, ti, tj);
  const int nkt = 256 / gridDim.y;  // k64-tiles per chunk
  const int t = threadIdx.x;
  const int lane = t & 63, w = t >> 6;
  const int wr = w >> 1, wc = w & 1;

  f32x4 acc[4][4];
#pragma unroll
  for (int m = 0; m < 4; ++m)
#pragma unroll
    for (int n = 0; n < 4; ++n) acc[m][n] = (f32x4){0.f, 0.f, 0.f, 0.f};

  const int rlow = lane & 15, g0 = lane >> 4;
  const int kt0 = c * nkt;

  for (int ks = 0; ks < nkt; ++ks) {
    const size_t ktbase = (size_t)(kt0 + ks) * (1024 * 64);
    const _Float16* __restrict__ sAh = hi_t + ktbase + (size_t)ti * 128 * 64;
    const _Float16* __restrict__ sAl = lo_t + ktbase + (size_t)ti * 128 * 64;
    const _Float16* __restrict__ sBh = hi_t + ktbase + (size_t)tj * 128 * 64;
    const _Float16* __restrict__ sBl = lo_t + ktbase + (size_t)tj * 128 * 64;
#pragma unroll
    for (int q = 0; q < 4; ++q) {
      const int off = (w * 4 + q) * 1024 + lane * 16;  // bytes
      __builtin_amdgcn_global_load_lds((gvoid_t*)((const char*)sAh + off),
                                       (svoid_t*)((char*)Ahi + (w * 4 + q) * 1024), 16, 0, 0);
      __builtin_amdgcn_global_load_lds((gvoid_t*)((const char*)sAl + off),
                                       (svoid_t*)((char*)Alo + (w * 4 + q) * 1024), 16, 0, 0);
      __builtin_amdgcn_global_load_lds((gvoid_t*)((const char*)sBh + off),
                                       (svoid_t*)((char*)Bhi + (w * 4 + q) * 1024), 16, 0, 0);
      __builtin_amdgcn_global_load_lds((gvoid_t*)((const char*)sBl + off),
                                       (svoid_t*)((char*)Blo + (w * 4 + q) * 1024), 16, 0, 0);
    }
    __syncthreads();

#pragma unroll
    for (int kk = 0; kk < 2; ++kk) {
      const int g = kk * 4 + g0;
      f16x8 fah[4], fal[4], fbh[4], fbl[4];
#pragma unroll
      for (int m = 0; m < 4; ++m) {
        const int ra = wr * 64 + m * 16 + rlow;
        const int pa = (g ^ (ra & 7)) * 8;
        fah[m] = *(const f16x8*)(Ahi + ra * 64 + pa);
        fal[m] = *(const f16x8*)(Alo + ra * 64 + pa);
        const int rb = wc * 64 + m * 16 + rlow;
        const int pb = (g ^ (rb & 7)) * 8;
        fbh[m] = *(const f16x8*)(Bhi + rb * 64 + pb);
        fbl[m] = *(const f16x8*)(Blo + rb * 64 + pb);
      }
#pragma unroll
      for (int m = 0; m < 4; ++m)
#pragma unroll
        for (int n = 0; n < 4; ++n) {
          acc[m][n] = __builtin_amdgcn_mfma_f32_16x16x32_f16(fah[m], fbh[n], acc[m][n], 0, 0, 0);
          acc[m][n] = __builtin_amdgcn_mfma_f32_16x16x32_f16(fal[m], fbh[n], acc[m][n], 0, 0, 0);
          acc[m][n] = __builtin_amdgcn_mfma_f32_16x16x32_f16(fah[m], fbl[n], acc[m][n], 0, 0, 0);
        }
    }
    __syncthreads();
  }

  // C/D layout: col = lane&15, row = (lane>>4)*4 + q (m89-verified)
  float* __restrict__ dst = part + ((size_t)c * NTILES + tt) * 16384;
  const int c_locb = wc * 64 + rlow;
  const int r_locb = wr * 64 + g0 * 4;
#pragma unroll
  for (int m = 0; m < 4; ++m)
#pragma unroll
    for (int q = 0; q < 4; ++q) {
      const int rl = r_locb + m * 16 + q;
#pragma unroll
      for (int n = 0; n < 4; ++n)
        dst[rl * 128 + c_locb + n * 16] = acc[m][n][q];
    }
}

// ---------------------------------------------------------------------------
// Sum split-K partials (fp64), unscale, write G tile + mirrored tile (LDS
// transpose, pad 129 = conflict-free), extract diagonal.
// Grid: 36 tiles x 4 slabs of 32 rows.
// ---------------------------------------------------------------------------
__global__ __launch_bounds__(256)
void reduce_tiles_k(const float* __restrict__ part, float* __restrict__ G,
                    float* __restrict__ diag, int nsplit) {
  __shared__ float sl[32][129];
  const int blk = blockIdx.x;  // 0..143
  const int tt = blk >> 2, s = blk & 3;
  int ti, tj;
  tri_map(tt, ti, tj);
  const int t = threadIdx.x;
  const int base_in = tt * 16384 + s * 4096;

  float vals[16];
#pragma unroll
  for (int j = 0; j < 16; ++j) {
    const int idx = j * 256 + t;  // 0..4095 within slab
    double a = 0.0;
    for (int c = 0; c < nsplit; ++c)
      a += (double)part[(size_t)c * (NTILES * 16384) + base_in + idx];
    vals[j] = (float)(a * INV_SCALE2);
  }
#pragma unroll
  for (int j = 0; j < 16; ++j) {
    const int idx = j * 256 + t;
    const int r = idx >> 7, cl = idx & 127;
    const int R = ti * 128 + s * 32 + r, C = tj * 128 + cl;
    G[(size_t)R * NPTS + C] = vals[j];
    if (R == C) diag[R] = vals[j];
    sl[r][cl] = vals[j];
  }
  if (ti == tj) return;
  __syncthreads();
#pragma unroll
  for (int j = 0; j < 16; ++j) {
    const int idx = j * 256 + t;
    const int r = idx & 31, cl = idx >> 5;
    G[(size_t)(tj * 128 + cl) * NPTS + ti * 128 + s * 32 + r] = sl[r][cl];
  }
}

// ---------------------------------------------------------------------------
// One symmetric Sinkhorn phase: 512 blocks x 4 waves; 1 wave = 1 row-task.
// pot layout: [0]=f_ba, [1]=g_ab, [2]=f_aa, [3]=g_bb (512 doubles each).
// ---------------------------------------------------------------------------
__global__ __launch_bounds__(256)
void sinkhorn_phase_k(const float* __restrict__ G, const float* __restrict__ diag,
                      const double* __restrict__ src, double* __restrict__ dst,
                      double eps, double inv_eps, double damp, int use_pot,
                      int do_avg) {
  const int w = threadIdx.x >> 6, lane = threadIdx.x & 63;
  const int id = blockIdx.x * 4 + w;  // 0..2047
  const int which = id >> 9, r = id & 511;
  int row_pt, col_base, pot_idx;
  if (which == 0)      { row_pt = r;       col_base = 512; pot_idx = 1; }
  else if (which == 1) { row_pt = 512 + r; col_base = 0;   pot_idx = 0; }
  else if (which == 2) { row_pt = r;       col_base = 0;   pot_idx = 2; }
  else                 { row_pt = 512 + r; col_base = 512; pot_idx = 3; }

  const double dr = (double)diag[row_pt];
  const double* __restrict__ pot = src + pot_idx * 512;
  const float* __restrict__ Grow = G + (size_t)row_pt * NPTS + col_base;
  const float* __restrict__ dcol = diag + col_base;

  double arg[8];
  double m = -1.0e300;
#pragma unroll
  for (int u = 0; u < 8; ++u) {
    const int j = lane + u * 64;
    const double C = 0.5 * (dr + (double)dcol[j]) - (double)Grow[j];
    const double p = use_pot ? pot[j] : 0.0;
    const double a = (p - C) * inv_eps - LOG_N;
    arg[u] = a;
    m = fmax(m, a);
  }
#pragma unroll
  for (int off = 32; off > 0; off >>= 1) m = fmax(m, __shfl_xor(m, off));
  double s = 0.0;
#pragma unroll
  for (int u = 0; u < 8; ++u) s += exp(arg[u] - m);
#pragma unroll
  for (int off = 32; off > 0; off >>= 1) s += __shfl_xor(s, off);
  if (lane == 0) {
    const double lse = m + log(s);
    const double val = -eps * lse * damp;
    dst[which * 512 + r] = do_avg ? 0.5 * (src[which * 512 + r] + val) : val;
  }
}

// ---------------------------------------------------------------------------
// Debiased unbalanced Sinkhorn loss.
// ---------------------------------------------------------------------------
__global__ __launch_bounds__(256)
void loss_k(const double* __restrict__ pot, float* __restrict__ out, int out_size,
            double w) {
  const int t = threadIdx.x;
  double s = 0.0;
  for (int i = t; i < 512; i += 256) {
    s += (exp(-pot[1024 + i] / RHO_C) - exp(-pot[i] / RHO_C)) +
         (exp(-pot[1536 + i] / RHO_C) - exp(-pot[512 + i] / RHO_C));
  }
#pragma unroll
  for (int off = 32; off > 0; off >>= 1) s += __shfl_xor(s, off);
  __shared__ double wsum[4];
  if ((t & 63) == 0) wsum[t >> 6] = s;
  __syncthreads();
  if (t == 0) {
    out[0] = (float)(w * (wsum[0] + wsum[1] + wsum[2] + wsum[3]) * (1.0 / 512.0));
    for (int i = 1; i < out_size; ++i) out[i] = 0.f;
  }
}

extern "C" void kernel_launch(void* const* d_in, const int* in_sizes, int n_in,
                              void* d_out, int out_size, void* d_ws, size_t ws_size,
                              hipStream_t stream) {
  const float* nd = (const float*)d_in[1];
  const float* gt = (const float*)d_in[2];
  float* out = (float*)d_out;
  char* ws = (char*)d_ws;

  const size_t GM = (size_t)NPTS * NPTS;     // 1M elems
  const size_t P16 = (size_t)NPTS * HW * 2;  // 32 MB per half
  int nsplit = 16;
  while (nsplit > 1 &&
         2 * P16 + (size_t)nsplit * NTILES * 16384 * 4 + GM * 4 + 65536 > ws_size)
    nsplit >>= 1;

  _Float16* hi_t = (_Float16*)ws;
  _Float16* lo_t = (_Float16*)(ws + P16);
  float* part = (float*)(ws + 2 * P16);
  const size_t partsz = (size_t)nsplit * NTILES * 16384 * 4;
  float* G = (float*)(ws + 2 * P16 + partsz);
  float* diag = (float*)(ws + 2 * P16 + partsz + GM * 4);
  double* pots = (double*)(ws + 2 * P16 + partsz + GM * 4 + 8192);

  convert_split_k<<<1024, 256, 0, stream>>>(nd, gt, hi_t, lo_t);
  gemm_mfma_k<<<dim3(NTILES, nsplit), 256, 0, stream>>>(hi_t, lo_t, part);
  reduce_tiles_k<<<144, 256, 0, stream>>>(part, G, diag, nsplit);

  const double eps_list[9] = {1.0, 1.0, 0.25, 0.0625, 0.015625,
                              0.00390625, 0.0009765625, 0.000244140625, 1e-4};
  double* p0 = pots;
  double* p1 = pots + 2048;
  {  // init at eps0 = 1.0, no inner potentials, no averaging
    const double eps = 1.0, d = 1.0 / (1.0 + eps / RHO_C);
    sinkhorn_phase_k<<<512, 256, 0, stream>>>(G, diag, p1, p0, eps, 1.0 / eps, d, 0, 0);
  }
  double* src = p0;
  double* dst = p1;
  for (int k = 0; k < 9; ++k) {  // symmetric averaged updates
    const double eps = eps_list[k], d = 1.0 / (1.0 + eps / RHO_C);
    sinkhorn_phase_k<<<512, 256, 0, stream>>>(G, diag, src, dst, eps, 1.0 / eps, d, 1, 1);
    double* tmp = src; src = dst; dst = tmp;
  }
  {  // final extrapolation at blur^2, no averaging
    const double eps = 1e-4, d = 1.0 / (1.0 + eps / RHO_C);
    sinkhorn_phase_k<<<512, 256, 0, stream>>>(G, diag, src, dst, eps, 1.0 / eps, d, 1, 0);
    double* tmp = src; src = dst; dst = tmp;
  }
  loss_k<<<1, 256, 0, stream>>>(src, out, out_size, RHO_C + 1e-4 * 0.5);
}